// Round 10
// baseline (130.144 us; speedup 1.0000x reference)
//
#include <hip/hip_runtime.h>
#include <hip/hip_bf16.h>
#include <stdint.h>

// out_re[b,i] = sum_{j,l} Re{ x[b,j,l] * k[i,j] * conj(k[i,l]) }
//   T_re = P·R + Q·M ; T_im = P·M + Q·(-R)   (A = K-frags in regs, B = X from LDS)
//   out_re[b,i] = sum_j T_re·p[i,j] - T_im·q[i,j]
// Round-10: T4 counted-vmcnt pipeline. 3 LDS buffers (48KB), one RAW
// __builtin_amdgcn_s_barrier per phase, asm s_waitcnt vmcnt(2) (NEVER 0 in the
// loop) so prefetch DMA stays in flight across barriers — removes the
// vmcnt(0)-drain convoy that made block lifetime ~27µs for ~2µs of work.
// Epilogue k-weights preloaded once as bf16 pairs (no in-phase global loads).

typedef __attribute__((ext_vector_type(8))) __bf16 bf16x8;
typedef __attribute__((ext_vector_type(4))) float f32x4;
typedef __attribute__((ext_vector_type(4))) unsigned int u32x4;

#define EDIM 128
#define FRAG_ELEMS 16384   // d_ws bf16 elems: P[0,16384) Q[16384,32768)

static __device__ inline bf16x8 neg8(bf16x8 v) {
    u32x4 u = __builtin_bit_cast(u32x4, v);
    u ^= (u32x4){0x80008000u, 0x80008000u, 0x80008000u, 0x80008000u};
    return __builtin_bit_cast(bf16x8, u);
}

// ---- pre-pass: K (f32 interleaved p,q) -> bf16 fragment streams P, Q ----
// frag f = nT*4+u; lane (li,s) holds K[nT*16+li][u*32+s*8 .. +8)
__global__ void kprep_kernel(const float* __restrict__ Kern, __bf16* __restrict__ kf)
{
    int id = blockIdx.x * 256 + threadIdx.x;    // 0..2047
    int f    = id >> 6;
    int lane = id & 63;
    int nT = f >> 2, u = f & 3;
    int li = lane & 15, s = lane >> 4;
    int i  = nT * 16 + li;
    int l0 = u * 32 + s * 8;
    const float* g = Kern + (((size_t)i * EDIM + l0) << 1);
    bf16x8 p, q;
#pragma unroll
    for (int e = 0; e < 8; ++e) {
        p[e] = (__bf16)g[2 * e];
        q[e] = (__bf16)g[2 * e + 1];
    }
    ((bf16x8*)kf)[id]                = p;
    ((bf16x8*)(kf + FRAG_ELEMS))[id] = q;
}

#define ASG(p) (__attribute__((address_space(1))) const void*)(p)
#define ASL(p) (__attribute__((address_space(3))) void*)(p)

__global__ __launch_bounds__(512, 4) void qmeas_kernel(
    const float* __restrict__ R, const float* __restrict__ M,
    const float* __restrict__ Kern, const __bf16* __restrict__ kf,
    float* __restrict__ out, int nout)
{
    __shared__ __align__(16) unsigned char smem[49152];   // 3 x 16KB (R 8K | M 8K)

    const int t    = threadIdx.x;
    const int lane = t & 63;
    const int w    = t >> 6;       // wave 0..7 = i-tile
    const int li   = lane & 15;
    const int s    = lane >> 4;    // 0..3
    const int b    = blockIdx.x;

    // ---- persistent A-fragments: K rows i0..i0+16 (32 VGPRs) ----
    const bf16x8* Pf = (const bf16x8*)kf;
    const bf16x8* Qf = (const bf16x8*)(kf + FRAG_ELEMS);
    bf16x8 pa[4], qa[4];
#pragma unroll
    for (int u = 0; u < 4; ++u) {
        pa[u] = Pf[((w << 2) | u) * 64 + lane];
        qa[u] = Qf[((w << 2) | u) * 64 + lane];
    }

    // ---- epilogue weights preloaded once, bf16-packed: kwp[h][2r]=p,[2r+1]=q
    // h = jh*4+jt; this lane needs k[i0+4s+r][h*16+li]  (32 VGPRs) ----
    const int i0 = w << 4;
    const float2* K2 = (const float2*)Kern;
    bf16x8 kwp[8];
#pragma unroll
    for (int h = 0; h < 8; ++h) {
#pragma unroll
        for (int r = 0; r < 4; ++r) {
            float2 kv = K2[(size_t)(i0 + (s << 2) + r) * EDIM + h * 16 + li];
            kwp[h][2 * r]     = (__bf16)kv.x;
            kwp[h][2 * r + 1] = (__bf16)kv.y;
        }
    }

    // ---- staging geometry (source-side XOR pre-swizzle, rule 21) ----
    const size_t xb    = (size_t)b * (EDIM * EDIM);
    const int    rl    = lane >> 3;                  // 0..7
    const int    colp  = ((lane & 7) ^ rl) << 2;     // swizzled col (floats)
    const int    sgrow = w * 8 + rl;                 // row in 64-row tile
    const float* gR = R + xb + (size_t)sgrow * EDIM + colp;
    const float* gM = M + xb + (size_t)sgrow * EDIM + colp;

    // phase p = jh*4 + u: stage X[jh*64+sgrow][u*32 + swizzled cols] into buf p%3
#define STAGE(p_)                                                               \
    do {                                                                        \
        const float* r_ = gR + (((p_) >> 2) * 64 * EDIM + ((p_) & 3) * 32);     \
        const float* m_ = gM + (((p_) >> 2) * 64 * EDIM + ((p_) & 3) * 32);     \
        unsigned char* d_ = smem + ((p_) % 3) * 16384 + w * 1024;               \
        __builtin_amdgcn_global_load_lds(ASG(r_), ASL(d_), 16, 0, 0);           \
        __builtin_amdgcn_global_load_lds(ASG(m_), ASL(d_ + 8192), 16, 0, 0);    \
    } while (0)

    STAGE(0);
    STAGE(1);

    f32x4 are[4], aim[4];
#pragma unroll
    for (int n = 0; n < 4; ++n) {
        are[n] = (f32x4){0.f, 0.f, 0.f, 0.f};
        aim[n] = (f32x4){0.f, 0.f, 0.f, 0.f};
    }
    float reS[4] = {0.f, 0.f, 0.f, 0.f};
    const int swz = (li & 7) << 4;

#pragma unroll
    for (int p = 0; p < 8; ++p) {
        // wait for STAGE(p) only; STAGE(p+1)'s 2 ops stay in flight
        if (p < 7) asm volatile("s_waitcnt vmcnt(2)" ::: "memory");
        else       asm volatile("s_waitcnt vmcnt(0)" ::: "memory");
        __builtin_amdgcn_s_barrier();          // RAW: all waves' STAGE(p) visible
        if (p < 6) STAGE(p + 2);               // WAR-safe: buf was read in p-1

        const unsigned char* base = smem + (p % 3) * 16384;
        const int u = p & 3;
#pragma unroll
        for (int jt = 0; jt < 4; ++jt) {
            const int row = (jt << 4) + li;
            const int a0  = row * 128 + ((s * 32) ^ swz);
            const int a1  = row * 128 + ((s * 32 + 16) ^ swz);
            f32x4 r0 = *(const f32x4*)(base + a0);
            f32x4 r1 = *(const f32x4*)(base + a1);
            f32x4 m0 = *(const f32x4*)(base + 8192 + a0);
            f32x4 m1 = *(const f32x4*)(base + 8192 + a1);
            bf16x8 xr, xm;
#pragma unroll
            for (int e = 0; e < 4; ++e) {
                xr[e]     = (__bf16)r0[e];
                xr[4 + e] = (__bf16)r1[e];
                xm[e]     = (__bf16)m0[e];
                xm[4 + e] = (__bf16)m1[e];
            }
            bf16x8 xrn = neg8(xr);
            are[jt] = __builtin_amdgcn_mfma_f32_16x16x32_bf16(pa[u], xr,  are[jt], 0, 0, 0);
            are[jt] = __builtin_amdgcn_mfma_f32_16x16x32_bf16(qa[u], xm,  are[jt], 0, 0, 0);
            aim[jt] = __builtin_amdgcn_mfma_f32_16x16x32_bf16(pa[u], xm,  aim[jt], 0, 0, 0);
            aim[jt] = __builtin_amdgcn_mfma_f32_16x16x32_bf16(qa[u], xrn, aim[jt], 0, 0, 0);
        }

        // ---- per-j-half epilogue: weight by k[i,j] (preloaded), fold ----
        if (u == 3) {
            const int jh = p >> 2;
#pragma unroll
            for (int jt = 0; jt < 4; ++jt) {
                const bf16x8 kv = kwp[jh * 4 + jt];
#pragma unroll
                for (int r = 0; r < 4; ++r) {
                    reS[r] += are[jt][r] * (float)kv[2 * r]
                            - aim[jt][r] * (float)kv[2 * r + 1];
                }
                are[jt] = (f32x4){0.f, 0.f, 0.f, 0.f};
                aim[jt] = (f32x4){0.f, 0.f, 0.f, 0.f};
            }
        }
    }

    // ---- reduce over li (16 lanes) and store: wave owns i0..i0+16 ----
#pragma unroll
    for (int r = 0; r < 4; ++r) {
        reS[r] += __shfl_xor(reS[r], 1);
        reS[r] += __shfl_xor(reS[r], 2);
        reS[r] += __shfl_xor(reS[r], 4);
        reS[r] += __shfl_xor(reS[r], 8);
    }
    if (li == 0) {
        int oi = b * EDIM + i0 + (s << 2);
        if (oi + 3 < nout) {
            f32x4 o;
            o[0] = reS[0]; o[1] = reS[1]; o[2] = reS[2]; o[3] = reS[3];
            *(f32x4*)(out + oi) = o;
        }
    }
}

extern "C" void kernel_launch(void* const* d_in, const int* in_sizes, int n_in,
                              void* d_out, int out_size, void* d_ws, size_t ws_size,
                              hipStream_t stream) {
    const float* R    = (const float*)d_in[0];
    const float* M    = (const float*)d_in[1];
    const float* Kern = (const float*)d_in[2];
    float*       out  = (float*)d_out;
    __bf16*      kf   = (__bf16*)d_ws;          // needs 64KB of ws
    const int    B    = in_sizes[0] / (EDIM * EDIM);   // 2048

    kprep_kernel<<<8, 256, 0, stream>>>(Kern, kf);
    qmeas_kernel<<<B, 512, 0, stream>>>(R, M, Kern, kf, out, out_size);
}

// Round 11
// 110.049 us; speedup vs baseline: 1.1826x; 1.1826x over previous
//
#include <hip/hip_runtime.h>
#include <hip/hip_bf16.h>
#include <stdint.h>

// out_re[b,i] = sum_{j,l} Re{ x[b,j,l]*k[i,j]*conj(k[i,l]) }, d_out = Re only.
// Round-11: l-split TLP. Grid = 2*B; block (b, q=blockIdx&1) computes the
// partial over l in [q*64, q*64+64) and atomicAdds into out (memset to 0 per
// call). Round-6 skeleton otherwise: K l-half staged as bf16 Pb/Qb in 32KB
// LDS (XOR-swizzled), X rows as A-frags (8 f32x4 loads/lane), nT-outer MFMA
// (live acc = 8 regs), f32 epilogue weights from L2, partials via 4KB LDS
// overlay. 32KB LDS -> 4 blocks/CU (wave-slot-limited, 100% slots) vs the
// 2-3 resident / 44% occupancy plateau of rounds 4-10.

typedef __attribute__((ext_vector_type(8))) __bf16 bf16x8;
typedef __attribute__((ext_vector_type(4))) float f32x4;
typedef __attribute__((ext_vector_type(4))) unsigned int u32x4;

#define EDIM 128

static __device__ inline bf16x8 neg8(bf16x8 v) {
    u32x4 u = __builtin_bit_cast(u32x4, v);
    u ^= (u32x4){0x80008000u, 0x80008000u, 0x80008000u, 0x80008000u};
    return __builtin_bit_cast(bf16x8, u);
}

__global__ __launch_bounds__(512, 4) void qmeas_kernel(
    const float* __restrict__ R, const float* __restrict__ M,
    const float* __restrict__ Kern, float* __restrict__ out, int nout)
{
    // [0,16K) Pb bf16[128][64], [16K,32K) Qb. part overlays [0,4K) at the end.
    __shared__ __align__(16) unsigned char smem[32768];

    const int t    = threadIdx.x;
    const int lane = t & 63;
    const int w    = t >> 6;       // wave 0..7
    const int li   = lane & 15;
    const int s    = lane >> 4;    // 0..3
    const int b    = blockIdx.x >> 1;
    const int q    = blockIdx.x & 1;    // l-half
    const int lq   = q * 64;            // global l offset of this half

    // ---- stage K l-half (f32 interleaved p,q -> bf16 Pb/Qb, swizzled) ----
    for (int it = 0; it < 2; ++it) {
        int idx = t + it * 512;            // 0..1023
        int i   = idx >> 3;                // row 0..127
        int c0  = (idx & 7) << 3;          // local col 0,8,...,56
        const float* g = Kern + (((size_t)i * EDIM + lq + c0) << 1);
        f32x4 f0 = *(const f32x4*)(g);
        f32x4 f1 = *(const f32x4*)(g + 4);
        f32x4 f2 = *(const f32x4*)(g + 8);
        f32x4 f3 = *(const f32x4*)(g + 12);
        bf16x8 pv, qv;
        pv[0] = (__bf16)f0[0]; qv[0] = (__bf16)f0[1];
        pv[1] = (__bf16)f0[2]; qv[1] = (__bf16)f0[3];
        pv[2] = (__bf16)f1[0]; qv[2] = (__bf16)f1[1];
        pv[3] = (__bf16)f1[2]; qv[3] = (__bf16)f1[3];
        pv[4] = (__bf16)f2[0]; qv[4] = (__bf16)f2[1];
        pv[5] = (__bf16)f2[2]; qv[5] = (__bf16)f2[3];
        pv[6] = (__bf16)f3[0]; qv[6] = (__bf16)f3[1];
        pv[7] = (__bf16)f3[2]; qv[7] = (__bf16)f3[3];
        int off = (i * 128 + (c0 << 1)) ^ ((i & 7) << 4);   // 128B rows
        *(bf16x8*)(smem + off)         = pv;   // Pb
        *(bf16x8*)(smem + 16384 + off) = qv;   // Qb
    }
    __syncthreads();

    // ---- load this wave's X rows for the l-half (8 f32x4), cvt to frags ----
    const int    jj = (w << 4) + li;              // this lane's A-row (j)
    const float* Rp = R + (size_t)b * (EDIM * EDIM) + (size_t)jj * EDIM + lq + s * 8;
    const float* Mp = M + (size_t)b * (EDIM * EDIM) + (size_t)jj * EDIM + lq + s * 8;

    f32x4 fr[4], fm[4];
#pragma unroll
    for (int u = 0; u < 2; ++u) {
        fr[2 * u]     = *(const f32x4*)(Rp + u * 32);
        fr[2 * u + 1] = *(const f32x4*)(Rp + u * 32 + 4);
        fm[2 * u]     = *(const f32x4*)(Mp + u * 32);
        fm[2 * u + 1] = *(const f32x4*)(Mp + u * 32 + 4);
    }
    bf16x8 ra[2], ma[2], rn[2];
#pragma unroll
    for (int u = 0; u < 2; ++u) {
#pragma unroll
        for (int e = 0; e < 4; ++e) {
            ra[u][e]     = (__bf16)fr[2 * u][e];
            ra[u][4 + e] = (__bf16)fr[2 * u + 1][e];
            ma[u][e]     = (__bf16)fm[2 * u][e];
            ma[u][4 + e] = (__bf16)fm[2 * u + 1][e];
        }
        rn[u] = neg8(ra[u]);
    }

    // ---- main: nT outer (live acc = 8 regs), u inner (2 l-chunks) ----
    // D layout: col i = lane&15, row j = jrow0 + reg, jrow0 = w*16 + s*4
    const int jrow0 = (w << 4) + (s << 2);
    float re8[8];
#pragma unroll
    for (int nT = 0; nT < 8; ++nT) {
        const int i = (nT << 4) + li;
        const float* kp = Kern + (((size_t)i * EDIM + jrow0) << 1);
        f32x4 k0 = *(const f32x4*)(kp);       // p0 q0 p1 q1
        f32x4 k1 = *(const f32x4*)(kp + 4);   // p2 q2 p3 q3
        f32x4 are = (f32x4){0.f, 0.f, 0.f, 0.f};
        f32x4 aim = (f32x4){0.f, 0.f, 0.f, 0.f};
#pragma unroll
        for (int u = 0; u < 2; ++u) {
            int off = (i * 128 + ((u * 64 + s * 16) ^ ((i & 7) << 4)));
            bf16x8 pB = *(const bf16x8*)(smem + off);
            bf16x8 qB = *(const bf16x8*)(smem + 16384 + off);
            are = __builtin_amdgcn_mfma_f32_16x16x32_bf16(ra[u], pB, are, 0, 0, 0);
            are = __builtin_amdgcn_mfma_f32_16x16x32_bf16(ma[u], qB, are, 0, 0, 0);
            aim = __builtin_amdgcn_mfma_f32_16x16x32_bf16(ma[u], pB, aim, 0, 0, 0);
            aim = __builtin_amdgcn_mfma_f32_16x16x32_bf16(rn[u], qB, aim, 0, 0, 0);
        }
        float re = are[0] * k0[0] - aim[0] * k0[1]
                 + are[1] * k0[2] - aim[1] * k0[3]
                 + are[2] * k1[0] - aim[2] * k1[1]
                 + are[3] * k1[2] - aim[3] * k1[3];
        re += __shfl_xor(re, 16);
        re += __shfl_xor(re, 32);
        re8[nT] = re;
    }

    // ---- all Pb/Qb reads done; overlay part f32[8][128] on smem[0,4K) ----
    __syncthreads();
    float* part = (float*)smem;
    if (s == 0) {
#pragma unroll
        for (int nT = 0; nT < 8; ++nT) {
            part[w * EDIM + (nT << 4) + li] = re8[nT];
        }
    }
    __syncthreads();

    // ---- cross-wave reduce + atomic combine of the two l-halves ----
    if (t < EDIM) {
        float sum = part[t];
#pragma unroll
        for (int ww = 1; ww < 8; ++ww) sum += part[ww * EDIM + t];
        int oi = b * EDIM + t;
        if (oi < nout) atomicAdd(out + oi, sum);
    }
}

extern "C" void kernel_launch(void* const* d_in, const int* in_sizes, int n_in,
                              void* d_out, int out_size, void* d_ws, size_t ws_size,
                              hipStream_t stream) {
    const float* R    = (const float*)d_in[0];
    const float* M    = (const float*)d_in[1];
    const float* Kern = (const float*)d_in[2];
    float*       out  = (float*)d_out;
    const int    B    = in_sizes[0] / (EDIM * EDIM);   // 2048

    hipMemsetAsync(d_out, 0, (size_t)out_size * sizeof(float), stream);
    qmeas_kernel<<<2 * B, 512, 0, stream>>>(R, M, Kern, out, out_size);
}

// Round 12
// 68.038 us; speedup vs baseline: 1.9128x; 1.6175x over previous
//
#include <hip/hip_runtime.h>
#include <hip/hip_bf16.h>
#include <stdint.h>

// out_re[b,i] = sum_{j,l} Re{ x[b,j,l]*k[i,j]*conj(k[i,l]) },  d_out = Re only.
//   T_re = P·R + Q·M ; T_im = P·M + Q·(-R)  (A = K-frags, B = X), then
//   out_re[b,i] = sum_j T_re*p[i,j] - T_im*q[i,j].
// Round-12: persistent blocks (grid=256, 8 batches each). K-frags DMA'd to LDS
// once (64KB); X streams through 2x32KB LDS buffers as j-quarter phases via
// global_load_lds with COUNTED vmcnt (never 0 mid-pipeline) + raw s_barrier.
// The batch loop has ZERO compiler-visible global loads (epilogue weights
// gathered from K-LDS as bf16) so the vmcnt queue is exclusively DMA ops.
// This is the Little's-law fix: ~32KB DMA in flight per CU vs the ~1-2
// serialized VGPR loads/wave the allocator produced in rounds 4-11.

typedef __attribute__((ext_vector_type(8))) __bf16 bf16x8;
typedef __attribute__((ext_vector_type(4))) float f32x4;
typedef __attribute__((ext_vector_type(4))) unsigned int u32x4;

#define EDIM 128
#define FRAG_ELEMS 16384    // ws bf16 elems: P[0,16384) Q[16384,32768)
#define NBAT 8
#define LDS_BYTES 131072
#define KQ_OFF 32768
#define X_OFF 65536
#define XBUF 32768
#define XM_OFF 16384

static __device__ inline bf16x8 neg8(bf16x8 v) {
    u32x4 u = __builtin_bit_cast(u32x4, v);
    u ^= (u32x4){0x80008000u, 0x80008000u, 0x80008000u, 0x80008000u};
    return __builtin_bit_cast(bf16x8, u);
}

// ---- pre-pass: K (f32 interleaved p,q) -> bf16 fragment streams P, Q ----
// frag f = nT*4+u; lane (li,s) holds K[nT*16+li][u*32+s*8 .. +8)
__global__ void kprep_kernel(const float* __restrict__ Kern, __bf16* __restrict__ kf)
{
    int id = blockIdx.x * 256 + threadIdx.x;    // 0..2047
    int f    = id >> 6;
    int lane = id & 63;
    int nT = f >> 2, u = f & 3;
    int li = lane & 15, s = lane >> 4;
    int i  = nT * 16 + li;
    int l0 = u * 32 + s * 8;
    const float* g = Kern + (((size_t)i * EDIM + l0) << 1);
    bf16x8 p, q;
#pragma unroll
    for (int e = 0; e < 8; ++e) {
        p[e] = (__bf16)g[2 * e];
        q[e] = (__bf16)g[2 * e + 1];
    }
    ((bf16x8*)kf)[id]                = p;
    ((bf16x8*)(kf + FRAG_ELEMS))[id] = q;
}

#define ASG(p) (__attribute__((address_space(1))) const void*)(p)
#define ASL(p) (__attribute__((address_space(3))) void*)(p)
#define WAITV(N_) asm volatile("s_waitcnt vmcnt(" #N_ ")" ::: "memory")
#define BARRIER() asm volatile("s_barrier" ::: "memory")

__global__ __launch_bounds__(512, 2) void qmeas_kernel(
    const float* __restrict__ R, const float* __restrict__ M,
    const __bf16* __restrict__ kf, float* __restrict__ out, int nout)
{
    extern __shared__ unsigned char smem[];   // KP 32K | KQ 32K | Xbuf0 32K | Xbuf1 32K

    const int t    = threadIdx.x;
    const int lane = t & 63;
    const int w    = t >> 6;       // wave 0..7 = i-tile
    const int li   = lane & 15;
    const int s    = lane >> 4;    // 0..3
    const int rhi  = lane >> 5;    // 0..1 (staging row-within-pair)
    const int key  = li & 7;       // X swizzle key on read
    const int bat0 = blockIdx.x * NBAT;

    // ---- K-frag DMA: ws -> LDS linear copy (8 x 1KB per wave) ----
#pragma unroll
    for (int kk = 0; kk < 8; ++kk) {
        int base = ((w << 3) + kk) * 1024;
        const unsigned char* src = (const unsigned char*)kf + base + lane * 16;
        __builtin_amdgcn_global_load_lds(ASG(src), ASL(smem + base), 16, 0, 0);
    }

    // stage X j-quarter p_ of batch (bat0+n_) into buf (p_&1); 4 DMA/wave
#define STAGE_X(n_, p_)                                                         \
    do {                                                                        \
        const size_t xb_ = (size_t)(bat0 + (n_)) * (EDIM * EDIM);               \
        unsigned char* db_ = smem + X_OFF + ((p_) & 1) * XBUF;                  \
        _Pragma("unroll")                                                       \
        for (int k2 = 0; k2 < 2; ++k2) {                                        \
            int rloc = (w << 2) + (k2 << 1);                                    \
            int rowg = (p_) * 32 + rloc + rhi;                                  \
            int colf = ((lane & 31) ^ ((rloc + rhi) & 7)) << 2;                 \
            const float* sR_ = R + xb_ + (size_t)rowg * EDIM + colf;            \
            const float* sM_ = M + xb_ + (size_t)rowg * EDIM + colf;            \
            unsigned char* d_ = db_ + rloc * 512;                               \
            __builtin_amdgcn_global_load_lds(ASG(sR_), ASL(d_), 16, 0, 0);      \
            __builtin_amdgcn_global_load_lds(ASG(sM_), ASL(d_ + XM_OFF), 16, 0, 0); \
        }                                                                       \
    } while (0)

    STAGE_X(0, 0);
    STAGE_X(0, 1);

    float reS[4] = {0.f, 0.f, 0.f, 0.f};

    // compute+fold one j-quarter phase from buf (p_&1); acc = 16 regs
#define COMPUTE_FOLD(p_)                                                        \
    do {                                                                        \
        const unsigned char* Xb = smem + X_OFF + ((p_) & 1) * XBUF;             \
        f32x4 are[2], aim[2];                                                   \
        are[0] = (f32x4){0.f,0.f,0.f,0.f}; are[1] = (f32x4){0.f,0.f,0.f,0.f};   \
        aim[0] = (f32x4){0.f,0.f,0.f,0.f}; aim[1] = (f32x4){0.f,0.f,0.f,0.f};   \
        _Pragma("unroll")                                                       \
        for (int u = 0; u < 4; ++u) {                                           \
            bf16x8 pa = *(const bf16x8*)(smem + ((w << 2) + u) * 1024 + lane * 16); \
            bf16x8 qa = *(const bf16x8*)(smem + KQ_OFF + ((w << 2) + u) * 1024 + lane * 16); \
            _Pragma("unroll")                                                   \
            for (int jt = 0; jt < 2; ++jt) {                                    \
                int rl = (jt << 4) + li;                                        \
                int c0 = (u << 3) + (s << 1);                                   \
                int a0 = rl * 512 + ((c0 ^ key) << 4);                          \
                int a1 = rl * 512 + (((c0 + 1) ^ key) << 4);                    \
                f32x4 r0 = *(const f32x4*)(Xb + a0);                            \
                f32x4 r1 = *(const f32x4*)(Xb + a1);                            \
                f32x4 m0 = *(const f32x4*)(Xb + XM_OFF + a0);                   \
                f32x4 m1 = *(const f32x4*)(Xb + XM_OFF + a1);                   \
                bf16x8 xr, xm;                                                  \
                _Pragma("unroll")                                               \
                for (int e = 0; e < 4; ++e) {                                   \
                    xr[e] = (__bf16)r0[e]; xr[4 + e] = (__bf16)r1[e];           \
                    xm[e] = (__bf16)m0[e]; xm[4 + e] = (__bf16)m1[e];           \
                }                                                               \
                bf16x8 xrn = neg8(xr);                                          \
                are[jt] = __builtin_amdgcn_mfma_f32_16x16x32_bf16(pa, xr,  are[jt], 0, 0, 0); \
                are[jt] = __builtin_amdgcn_mfma_f32_16x16x32_bf16(qa, xm,  are[jt], 0, 0, 0); \
                aim[jt] = __builtin_amdgcn_mfma_f32_16x16x32_bf16(pa, xm,  aim[jt], 0, 0, 0); \
                aim[jt] = __builtin_amdgcn_mfma_f32_16x16x32_bf16(qa, xrn, aim[jt], 0, 0, 0); \
            }                                                                   \
        }                                                                       \
        const __bf16* KPb = (const __bf16*)smem;                                \
        const __bf16* KQb = (const __bf16*)(smem + KQ_OFF);                     \
        _Pragma("unroll")                                                       \
        for (int jt = 0; jt < 2; ++jt) {                                        \
            int lanep = ((( jt << 1) + (li >> 3)) & 3) << 4;                    \
            int fbase = (((w << 2) + (p_)) << 6) + lanep + (s << 2);            \
            _Pragma("unroll")                                                   \
            for (int r = 0; r < 4; ++r) {                                       \
                int ei = ((fbase + r) << 3) + (li & 7);                         \
                float pw = (float)KPb[ei], qw = (float)KQb[ei];                 \
                reS[r] += are[jt][r] * pw - aim[jt][r] * qw;                    \
            }                                                                   \
        }                                                                       \
    } while (0)

    for (int n = 0; n < NBAT; ++n) {
        // p0
        WAITV(4); BARRIER();
        COMPUTE_FOLD(0);
        BARRIER();
        STAGE_X(n, 2);
        // p1
        WAITV(4); BARRIER();
        COMPUTE_FOLD(1);
        BARRIER();
        STAGE_X(n, 3);
        // p2
        WAITV(4); BARRIER();
        COMPUTE_FOLD(2);
        BARRIER();
        if (n + 1 < NBAT) STAGE_X(n + 1, 0);
        // p3
        if (n + 1 < NBAT) { WAITV(4); } else { WAITV(0); }
        BARRIER();
        COMPUTE_FOLD(3);
        // store this batch: reduce reS over li, lanes li==0 write f32x4
#pragma unroll
        for (int r = 0; r < 4; ++r) {
            reS[r] += __shfl_xor(reS[r], 1);
            reS[r] += __shfl_xor(reS[r], 2);
            reS[r] += __shfl_xor(reS[r], 4);
            reS[r] += __shfl_xor(reS[r], 8);
        }
        if (li == 0) {
            int oi = (bat0 + n) * EDIM + (w << 4) + (s << 2);
            if (oi + 3 < nout) {
                f32x4 o;
                o[0] = reS[0]; o[1] = reS[1]; o[2] = reS[2]; o[3] = reS[3];
                *(f32x4*)(out + oi) = o;
            }
        }
        reS[0] = reS[1] = reS[2] = reS[3] = 0.f;
        BARRIER();
        if (n + 1 < NBAT) STAGE_X(n + 1, 1);
    }
}

extern "C" void kernel_launch(void* const* d_in, const int* in_sizes, int n_in,
                              void* d_out, int out_size, void* d_ws, size_t ws_size,
                              hipStream_t stream) {
    const float* R    = (const float*)d_in[0];
    const float* M    = (const float*)d_in[1];
    const float* Kern = (const float*)d_in[2];
    float*       out  = (float*)d_out;
    __bf16*      kf   = (__bf16*)d_ws;          // needs 64KB of ws
    const int    B    = in_sizes[0] / (EDIM * EDIM);   // 2048

    hipFuncSetAttribute((const void*)qmeas_kernel,
                        hipFuncAttributeMaxDynamicSharedMemorySize, LDS_BYTES);

    kprep_kernel<<<8, 256, 0, stream>>>(Kern, kf);
    int grid = B / NBAT;   // 256
    qmeas_kernel<<<grid, 512, LDS_BYTES, stream>>>(R, M, kf, out, out_size);
}